// Round 4
// baseline (241.971 us; speedup 1.0000x reference)
//
#include <hip/hip_runtime.h>
#include <hip/hip_cooperative_groups.h>
#include <math.h>

namespace cg = cooperative_groups;

#define BB 64
#define LL 512
#define DD 512
#define CC 50
#define NC 100
#define NCP 112
#define WST 520     // LDS row stride (bf16 units): bank step 4 -> 2-way max

// ws byte layout:
//   0: loss f32   4: cnt f32   8: done counter (int)
//   28736:   span partials bf16 [8 seg][64 b][512] (524288 B)
//   553024:  Wtop bf16 [112][512] (rows 100..111 = poison, excluded in epilogue)
//   667712:  Wbot bf16 [112][512]
#define WSB_LOSS  0
#define WSB_CNT   4
#define WSB_DONE  8
#define WSB_PART  28736
#define WSB_WTOP  553024
#define WSB_WBOT  667712

typedef __attribute__((ext_vector_type(8))) short bf16x8;
typedef __attribute__((ext_vector_type(4))) float f32x4;

static __device__ __forceinline__ unsigned short f2bf(float x) {
    unsigned int u = __float_as_uint(x);
    u += 0x7FFFu + ((u >> 16) & 1u);          // RNE
    return (unsigned short)(u >> 16);
}
static __device__ __forceinline__ float bf2f(unsigned short h) {
    return __uint_as_float(((unsigned int)h) << 16);
}

// ---------------------------------------------------------------------------
// k_fused: ONE cooperative kernel, 256 blocks x 512 thr (1 block/CU, exactly
// co-resident on 256 CUs). Replaces the old k_prep + k_main pair; all
// arithmetic is bit-identical to the two-kernel version — only the launch
// boundary became a grid sync.
//
// PRE-SYNC (producer phase):
//   - A preload issue: this block's 128 tv rows (32 float4/thread).
//   - span partial units 2g, 2g+1 (threads split 256/256) — the old k_prep
//     span blocks verbatim -> partials bf16 [8 seg][64 b][512] in ws.
//   - blocks 248..255: the 16 W-transpose jobs (2 sequential 512-thr jobs
//     each) -> Wtop/Wbot bf16 in ws.
//   - block 0: zero loss/cnt/done (agent-scope atomic stores).
//   - A convert -> bf16 regs; label/mask prefetch.
//   - __threadfence() (agent fence: L2 writeback — per-XCD L2s are NOT
//     coherent; consumers are on other XCDs) + grid.sync().
// POST-SYNC (consumer phase = old k_main body, unchanged):
//   - Wt (Wtop) LDS staging; sbjb combine from partials; barrier.
//   - phase 1: waves 0..6 broadcast-A MFMA sbj x Wbot -> scl (+bias).
//   - phase 2: pure LDS+MFMA burst (112 MFMAs/wave); barrier.
//   - fused CE epilogue; device atomics + done-counter; last block writes out.
// Cross-block safety: partials/Wtop/Wbot lines are never cached by their
// readers pre-sync (readers only touch their own batch's 2 self-written
// rows), so post-sync plain loads miss to the coherent point, which the
// pre-sync fence populated. (G16-compliant.)
// ---------------------------------------------------------------------------
__global__ __launch_bounds__(512, 1) void k_fused(
    const float* __restrict__ tv,
    const int* __restrict__ mask,
    const int* __restrict__ obj_s, const int* __restrict__ obj_e,
    const int* __restrict__ sbj_bound,
    const float* __restrict__ Wst, const float* __restrict__ bst,
    const float* __restrict__ Wen, const float* __restrict__ ben,
    char* __restrict__ wsb, float* __restrict__ out)
{
    __shared__ __align__(16) unsigned short Wt[NCP * WST];   // 116480 B
    __shared__ float sh[128 * 53];                           // 27136 B (W jobs)
    __shared__ __align__(16) float4 spanbuf[512];            // 8192 B
    __shared__ __align__(16) unsigned short sbjb[DD];        // 1024 B
    __shared__ float scl[NCP];                               // 448 B
    __shared__ float red[16];                                // total ~153 KB < 160

    const int t = threadIdx.x, g = blockIdx.x;
    const int wv = t >> 6, ln = t & 63;
    const int tc = ln & 15, quad = ln >> 4;
    const int m0w = g * 128 + wv * 16;
    const int b = g >> 2;

    // ---- A preload issue: 32 float4 in flight (this block's tv rows) ----
    const float* Abase = tv + (size_t)(m0w + tc) * DD + quad * 8;
    float4 a[32];
#pragma unroll
    for (int j = 0; j < 8; j++) {
        a[2 * j]      = *(const float4*)(Abase + j * 32);
        a[2 * j + 1]  = *(const float4*)(Abase + j * 32 + 4);
    }
#pragma unroll
    for (int j = 0; j < 8; j++) {
        a[16 + 2 * j] = *(const float4*)(Abase + 256 + j * 32);
        a[17 + 2 * j] = *(const float4*)(Abase + 256 + j * 32 + 4);
    }

    // ---- span partial units 2g (thr 0-255) and 2g+1 (thr 256-511) ----
    // (old k_prep span block, verbatim; unit = (b<<3)|seg)
    {
        const int half = t >> 8, t2 = t & 255;
        const int unit = g * 2 + half;
        const int sb = unit >> 3, seg = unit & 7;
        const int start = sbj_bound[2 * sb], end = sbj_bound[2 * sb + 1];
        int r0 = seg * 64;      if (r0 < start) r0 = start;
        int r1 = seg * 64 + 63; if (r1 > end)   r1 = end;
        const int c4 = t2 & 127, par = t2 >> 7;
        const float* bp = tv + (size_t)sb * LL * DD + c4 * 4;
        float4 a0 = {0, 0, 0, 0}, a1 = {0, 0, 0, 0};
        int r = r0 + par;
        for (; r + 2 <= r1; r += 4) {
            float4 v0 = *(const float4*)(bp + (size_t)r * DD);
            float4 v1 = *(const float4*)(bp + (size_t)(r + 2) * DD);
            a0.x += v0.x; a0.y += v0.y; a0.z += v0.z; a0.w += v0.w;
            a1.x += v1.x; a1.y += v1.y; a1.z += v1.z; a1.w += v1.w;
        }
        for (; r <= r1; r += 2) {
            float4 v0 = *(const float4*)(bp + (size_t)r * DD);
            a0.x += v0.x; a0.y += v0.y; a0.z += v0.z; a0.w += v0.w;
        }
        float4* buf = spanbuf + half * 256;
        float4 acc = {a0.x + a1.x, a0.y + a1.y, a0.z + a1.z, a0.w + a1.w};
        buf[t2] = acc;
        __syncthreads();
        if (t2 < 128) {
            float4 x = buf[t2], y = buf[t2 + 128];
            unsigned short* part = (unsigned short*)(wsb + WSB_PART);
            ushort4 o;
            o.x = f2bf(x.x + y.x); o.y = f2bf(x.y + y.y);
            o.z = f2bf(x.z + y.z); o.w = f2bf(x.w + y.w);
            *(ushort4*)(part + ((size_t)(seg * BB + sb)) * DD + t2 * 4) = o;
        }
    }

    // ---- W transpose/convert: blocks 248..255, 2 sequential jobs each ----
    if (g >= 248) {
#pragma unroll 1
        for (int rep = 0; rep < 2; rep++) {
            const int bi = (g - 248) * 2 + rep;    // 0..15
            const int mat = bi >> 3;               // 0: W_start, 1: W_end
            const int cj = bi & 7;                 // 128-row k-chunk of [0,1024)
            const float* W = mat ? Wen : Wst;
            const int kbase = cj * 128;
            const float* src = W + (size_t)kbase * CC;
            __syncthreads();                       // sh reuse across reps
#pragma unroll
            for (int i = 0; i < 13; i++) {
                int idx = t + i * 512;             // [0,6656) covers 6400
                if (idx < 6400) {
                    int kr = idx / 50, c = idx - kr * 50;
                    sh[kr * 53 + c] = src[idx];
                }
            }
            __syncthreads();
            unsigned short* outp =
                (unsigned short*)(wsb + ((cj < 4) ? WSB_WTOP : WSB_WBOT));
            const int kout = kbase & 511;
#pragma unroll
            for (int i = 0; i < 13; i++) {
                int idx = t + i * 512;             // 50 n x 128 k
                if (idx < 6400) {
                    int n = idx >> 7, kl = idx & 127;
                    outp[((size_t)(mat * CC + n)) * DD + kout + kl] =
                        f2bf(sh[kl * 53 + n]);
                }
            }
        }
    }

    // ---- zero the cross-block scalars (device-visible) ----
    if (g == 0 && t == 0) {
        __hip_atomic_store((float*)(wsb + WSB_LOSS), 0.0f,
                           __ATOMIC_RELAXED, __HIP_MEMORY_SCOPE_AGENT);
        __hip_atomic_store((float*)(wsb + WSB_CNT), 0.0f,
                           __ATOMIC_RELAXED, __HIP_MEMORY_SCOPE_AGENT);
        __hip_atomic_store((int*)(wsb + WSB_DONE), 0,
                           __ATOMIC_RELAXED, __HIP_MEMORY_SCOPE_AGENT);
    }

    // ---- convert A -> bf16 regs (a[] dies here) ----
    bf16x8 areg[16];
#pragma unroll
    for (int j = 0; j < 16; j++) {
        float4 v0 = a[2 * j], v1 = a[2 * j + 1];
        bf16x8 af;
        af[0] = (short)f2bf(v0.x); af[1] = (short)f2bf(v0.y);
        af[2] = (short)f2bf(v0.z); af[3] = (short)f2bf(v0.w);
        af[4] = (short)f2bf(v1.x); af[5] = (short)f2bf(v1.y);
        af[6] = (short)f2bf(v1.z); af[7] = (short)f2bf(v1.w);
        areg[j] = af;
    }
    // epilogue operand prefetch
    int lab1[4], lab2[4], mk[4];
#pragma unroll
    for (int i = 0; i < 4; i++) {
        const int l = (m0w + quad * 4 + i) & (LL - 1);
        lab1[i] = obj_s[b * LL + l];
        lab2[i] = obj_e[b * LL + l] + CC;
        mk[i]   = mask[b * LL + l];
    }

    // ---- producer -> consumer boundary (was the kernel boundary) ----
    __threadfence();               // agent fence: L2 writeback of partials/W
    cg::this_grid().sync();

    // ---- Wt (Wtop) LDS staging: 14 bf16x8/thread, coalesced ----
    const unsigned short* wtop = (const unsigned short*)(wsb + WSB_WTOP);
#pragma unroll
    for (int i = 0; i < 14; i++) {
        int idx = t + i * 512;
        int n = idx >> 6, ch = idx & 63;
        *(bf16x8*)(Wt + n * WST + ch * 8) =
            *(const bf16x8*)(wtop + (size_t)n * DD + ch * 8);
    }
    // sbj row: combine 8 bf16 seg-partials, / span count (identical math)
    {
        const unsigned short* part = (const unsigned short*)(wsb + WSB_PART);
        const float inv =
            1.0f / (float)(sbj_bound[2 * b + 1] - sbj_bound[2 * b] + 1);
        float s = 0.0f;
#pragma unroll
        for (int seg = 0; seg < 8; seg++)
            s += bf2f(part[(size_t)(seg * BB + b) * DD + t]);
        sbjb[t] = f2bf(s * inv);
    }
    __syncthreads();

    // ---- phase 1: scomb strips (waves 0..6), broadcast-A MFMA ----
    if (wv < 7) {
        const unsigned short* wbot = (const unsigned short*)(wsb + WSB_WBOT);
        const unsigned short* Bf = wbot + (size_t)(wv * 16 + tc) * DD + quad * 8;
        const unsigned short* Af2 = sbjb + quad * 8;
        f32x4 sacc = (f32x4)(0.0f);
#pragma unroll
        for (int kk = 0; kk < DD; kk += 32) {
            bf16x8 af = *(const bf16x8*)(Af2 + kk);
            bf16x8 bf = *(const bf16x8*)(Bf + kk);
            sacc = __builtin_amdgcn_mfma_f32_16x16x32_bf16(af, bf, sacc, 0, 0, 0);
        }
        if (ln < 16) {
            const int cc = wv * 16 + ln;
            const float bias =
                (cc < CC) ? bst[cc] : ((cc < NC) ? ben[cc - CC] : 0.0f);
            scl[cc] = sacc[0] + bias;
        }
    }

    // ---- phase 2: main burst, pure LDS+MFMA ----
    f32x4 acc[7];
#pragma unroll
    for (int u = 0; u < 7; u++) acc[u] = (f32x4)(0.0f);
    const unsigned short* Wf = Wt + tc * WST + quad * 8;

#pragma unroll
    for (int j = 0; j < 16; j++) {
        bf16x8 af = areg[j];
#pragma unroll
        for (int u = 0; u < 7; u++) {
            bf16x8 bf = *(const bf16x8*)(Wf + u * 16 * WST + j * 32);
            acc[u] = __builtin_amdgcn_mfma_f32_16x16x32_bf16(af, bf, acc[u], 0, 0, 0);
        }
    }
    __syncthreads();        // scl ready for all waves

    // ---- fused CE epilogue (C/D: col=lane&15, row=quad*4+reg) ----
    float sc[7];
#pragma unroll
    for (int u = 0; u < 7; u++) sc[u] = scl[u * 16 + tc];

    float loss_local = 0.0f, cnt_local = 0.0f;
#pragma unroll
    for (int i = 0; i < 4; i++) {
        float lg[7];
#pragma unroll
        for (int u = 0; u < 7; u++) lg[u] = acc[u][i] + sc[u];
        float m1 = fmaxf(fmaxf(lg[0], lg[1]), lg[2]);
        if (tc < 2) m1 = fmaxf(m1, lg[3]);
        float m2 = fmaxf(lg[4], lg[5]);
        if (tc >= 2) m2 = fmaxf(m2, lg[3]);
        if (tc < 4)  m2 = fmaxf(m2, lg[6]);
#pragma unroll
        for (int off = 1; off < 16; off <<= 1) {
            m1 = fmaxf(m1, __shfl_xor(m1, off, 16));
            m2 = fmaxf(m2, __shfl_xor(m2, off, 16));
        }
        float e1 = expf(lg[0] - m1) + expf(lg[1] - m1) + expf(lg[2] - m1)
                 + ((tc < 2) ? expf(lg[3] - m1) : 0.0f);
        float e2 = expf(lg[4] - m2) + expf(lg[5] - m2)
                 + ((tc >= 2) ? expf(lg[3] - m2) : 0.0f)
                 + ((tc < 4)  ? expf(lg[6] - m2) : 0.0f);
        float t1 = 0.0f, t2 = 0.0f;
#pragma unroll
        for (int u = 0; u < 7; u++) {
            const int cc = u * 16 + tc;
            if (cc == lab1[i]) t1 = lg[u];
            if (cc == lab2[i]) t2 = lg[u];
        }
#pragma unroll
        for (int off = 1; off < 16; off <<= 1) {
            e1 += __shfl_xor(e1, off, 16);
            e2 += __shfl_xor(e2, off, 16);
            t1 += __shfl_xor(t1, off, 16);
            t2 += __shfl_xor(t2, off, 16);
        }
        if (tc == 0) {
            const float nll = (m1 + logf(e1) - t1) + (m2 + logf(e2) - t2);
            loss_local += mk[i] ? nll : 0.0f;
            cnt_local  += mk[i] ? 1.0f : 0.0f;
        }
    }
#pragma unroll
    for (int off = 1; off < 64; off <<= 1) {
        loss_local += __shfl_xor(loss_local, off);
        cnt_local  += __shfl_xor(cnt_local, off);
    }
    if (ln == 0) { red[wv * 2] = loss_local; red[wv * 2 + 1] = cnt_local; }
    __syncthreads();
    if (t == 0) {
        float Ls = 0.f, Cs = 0.f;
#pragma unroll
        for (int w = 0; w < 8; w++) { Ls += red[w * 2]; Cs += red[w * 2 + 1]; }
        float* wsf = (float*)wsb;
        atomicAdd(&wsf[0], Ls);
        atomicAdd(&wsf[1], Cs);
        __threadfence();
        int old = atomicAdd((int*)(wsb + WSB_DONE), 1);
        if (old == (int)gridDim.x - 1) {
            float L = atomicAdd(&wsf[0], 0.0f);   // coherent read
            float C = atomicAdd(&wsf[1], 0.0f);
            out[0] = L / C;
        }
    }
}

extern "C" void kernel_launch(void* const* d_in, const int* in_sizes, int n_in,
                              void* d_out, int out_size, void* d_ws, size_t ws_size,
                              hipStream_t stream) {
    const float* tv   = (const float*)d_in[0];
    const int*   mask = (const int*)d_in[1];
    const int*   sbj  = (const int*)d_in[2];
    const int*   objs = (const int*)d_in[3];
    const int*   obje = (const int*)d_in[4];
    const float* Wst  = (const float*)d_in[5];
    const float* bst  = (const float*)d_in[6];
    const float* Wen  = (const float*)d_in[7];
    const float* ben  = (const float*)d_in[8];
    float* out = (float*)d_out;
    char*  wsb = (char*)d_ws;

    void* args[] = { &tv, &mask, &objs, &obje, &sbj,
                     &Wst, &bst, &Wen, &ben, &wsb, &out };
    hipLaunchCooperativeKernel((void*)k_fused, dim3(256), dim3(512),
                               args, 0, stream);
}

// Round 5
// 136.423 us; speedup vs baseline: 1.7737x; 1.7737x over previous
//
#include <hip/hip_runtime.h>
#include <math.h>

#define BB 64
#define LL 512
#define DD 512
#define CC 50
#define NC 100
#define NCP 112
#define WST 520     // LDS row stride (bf16 units): bank step 4 -> 2-way max

// ws byte layout:
//   0: loss f32   4: cnt f32   8: done counter (int)
//   28736:   span partials bf16 [8 seg][64 b][512] (524288 B)
//   553024:  Wtop bf16 [112][512] (rows 100..111 = poison, excluded in epilogue)
//   667712:  Wbot bf16 [112][512]
#define WSB_LOSS  0
#define WSB_CNT   4
#define WSB_DONE  8
#define WSB_PART  28736
#define WSB_WTOP  553024
#define WSB_WBOT  667712

typedef __attribute__((ext_vector_type(8))) short bf16x8;
typedef __attribute__((ext_vector_type(4))) float f32x4;

static __device__ __forceinline__ unsigned short f2bf(float x) {
    unsigned int u = __float_as_uint(x);
    u += 0x7FFFu + ((u >> 16) & 1u);          // RNE
    return (unsigned short)(u >> 16);
}
static __device__ __forceinline__ float bf2f(unsigned short h) {
    return __uint_as_float(((unsigned int)h) << 16);
}

// ---------------------------------------------------------------------------
// k_prep: blocks [0,512): span partials. block=(b<<3)|seg; rows
//   [seg*64, seg*64+64) ∩ [start,end] summed -> bf16 partial[seg][b][512].
//   Empty segments write ZEROS (no early return).
// blocks [512,528): W transpose/convert -> Wtop/Wbot bf16 [100][512].
// block 512 zeroes loss/cnt/done.
// ---------------------------------------------------------------------------
__global__ __launch_bounds__(256) void k_prep(
    const float* __restrict__ tv, const int* __restrict__ sbj_bound,
    const float* __restrict__ Wst, const float* __restrict__ Wen,
    char* __restrict__ wsb)
{
    __shared__ float sh[128 * 53];
    const int t = threadIdx.x;
    const int blk = blockIdx.x;

    if (blk < 512) {
        const int b = blk >> 3, seg = blk & 7;
        const int start = sbj_bound[2 * b], end = sbj_bound[2 * b + 1];
        int r0 = seg * 64;      if (r0 < start) r0 = start;
        int r1 = seg * 64 + 63; if (r1 > end)   r1 = end;
        const int c4 = t & 127, par = t >> 7;
        const float* bp = tv + (size_t)b * LL * DD + c4 * 4;
        float4 a0 = {0, 0, 0, 0}, a1 = {0, 0, 0, 0};
        int r = r0 + par;
        for (; r + 2 <= r1; r += 4) {
            float4 v0 = *(const float4*)(bp + (size_t)r * DD);
            float4 v1 = *(const float4*)(bp + (size_t)(r + 2) * DD);
            a0.x += v0.x; a0.y += v0.y; a0.z += v0.z; a0.w += v0.w;
            a1.x += v1.x; a1.y += v1.y; a1.z += v1.z; a1.w += v1.w;
        }
        for (; r <= r1; r += 2) {
            float4 v0 = *(const float4*)(bp + (size_t)r * DD);
            a0.x += v0.x; a0.y += v0.y; a0.z += v0.z; a0.w += v0.w;
        }
        float4* buf = (float4*)sh;
        float4 acc = {a0.x + a1.x, a0.y + a1.y, a0.z + a1.z, a0.w + a1.w};
        buf[t] = acc;
        __syncthreads();
        if (t < 128) {
            float4 x = buf[t], y = buf[t + 128];
            unsigned short* part = (unsigned short*)(wsb + WSB_PART);
            ushort4 o;
            o.x = f2bf(x.x + y.x); o.y = f2bf(x.y + y.y);
            o.z = f2bf(x.z + y.z); o.w = f2bf(x.w + y.w);
            *(ushort4*)(part + ((size_t)(seg * BB + b)) * DD + t * 4) = o;
        }
    } else {
        const int bi = blk - 512;              // 0..15
        const int mat = bi >> 3;               // 0: W_start, 1: W_end
        const int cj = bi & 7;                 // 128-row k-chunk of [0,1024)
        const float* W = mat ? Wen : Wst;
        const int kbase = cj * 128;
        const float* src = W + (size_t)kbase * CC;
#pragma unroll
        for (int i = 0; i < 25; i++) {
            int idx = t + i * 256;             // [0,6400)
            int kr = idx / 50, c = idx - kr * 50;
            sh[kr * 53 + c] = src[idx];
        }
        __syncthreads();
        unsigned short* outp =
            (unsigned short*)(wsb + ((cj < 4) ? WSB_WTOP : WSB_WBOT));
        const int kout = kbase & 511;
#pragma unroll
        for (int i = 0; i < 25; i++) {
            int idx = t + i * 256;             // 50 n x 128 k
            int n = idx >> 7, kl = idx & 127;
            outp[((size_t)(mat * CC + n)) * DD + kout + kl] = f2bf(sh[kl * 53 + n]);
        }
        if (bi == 0 && t == 0) {
            *(float*)(wsb + WSB_LOSS) = 0.0f;
            *(float*)(wsb + WSB_CNT)  = 0.0f;
            *(int*)(wsb + WSB_DONE)   = 0;
        }
    }
}

// ---------------------------------------------------------------------------
// k_main: 256 blocks x 512 thr (1 block/CU, 8 waves). Fused scomb (each
// block rebuilds its batch's 112 scomb values; 4x redundant, trivial cost).
// SINGLE LOAD BURST prologue — all 32 A float4s + 14 B-stage loads +
// sbj-partial loads + label loads issued before any dependent consumption.
// Peak regs ~190 < 256 budget from (512,1): no scratch spill.
//   phase 1 (wv 0..6): broadcast-A MFMA sbj x Wbot(global, L2-hot) -> scl.
//   phase 2: pure LDS+MFMA main burst (112 MFMAs/wave); fused CE epilogue.
// NOTE (R4 lesson): do NOT fuse k_prep into this kernel — the data-dependent
// span loop ahead of the A-preload wrecks regalloc (VGPR 116, scratch
// serialization, 130 µs warm-cache) and the grid sync gates on the slowest
// producer block. Two-kernel split is the known-good structure.
// ---------------------------------------------------------------------------
__global__ __launch_bounds__(512, 1) void k_main(
    const float* __restrict__ tv,
    const int* __restrict__ mask,
    const int* __restrict__ obj_s, const int* __restrict__ obj_e,
    const int* __restrict__ sbj_bound,
    const float* __restrict__ bst, const float* __restrict__ ben,
    char* __restrict__ wsb, float* __restrict__ out)
{
    __shared__ __align__(16) unsigned short Wt[NCP * WST];   // 116480 B
    __shared__ __align__(16) unsigned short sbjb[DD];        // 1024 B
    __shared__ float scl[NCP];                               // 448 B
    __shared__ float red[16];
    const int t = threadIdx.x, wv = t >> 6, ln = t & 63;
    const int tc = ln & 15, quad = ln >> 4;
    const int m0w = blockIdx.x * 128 + wv * 16;
    const int b = blockIdx.x >> 2;
    const unsigned short* wtop = (const unsigned short*)(wsb + WSB_WTOP);

    const float* Abase = tv + (size_t)(m0w + tc) * DD + quad * 8;

    // ---- single load burst: everything independent issued up front ----
    float4 a[32];
#pragma unroll
    for (int j = 0; j < 8; j++) {
        a[2 * j]      = *(const float4*)(Abase + j * 32);
        a[2 * j + 1]  = *(const float4*)(Abase + j * 32 + 4);
    }
#pragma unroll
    for (int j = 0; j < 8; j++) {
        a[16 + 2 * j] = *(const float4*)(Abase + 256 + j * 32);
        a[17 + 2 * j] = *(const float4*)(Abase + 256 + j * 32 + 4);
    }
    // stage B: 112 rows x 64 chunks-of-8 = 7168; 14 per thread, coalesced
#pragma unroll
    for (int i = 0; i < 14; i++) {
        int idx = t + i * 512;
        int n = idx >> 6, ch = idx & 63;
        *(bf16x8*)(Wt + n * WST + ch * 8) =
            *(const bf16x8*)(wtop + (size_t)n * DD + ch * 8);
    }
    // sbj row for this batch: combine 8 bf16 seg-partials, / span count
    // (identical math to before: f32 sum over segs, *inv, RNE)
    {
        const unsigned short* part = (const unsigned short*)(wsb + WSB_PART);
        const float inv =
            1.0f / (float)(sbj_bound[2 * b + 1] - sbj_bound[2 * b] + 1);
        float s = 0.0f;
#pragma unroll
        for (int seg = 0; seg < 8; seg++)
            s += bf2f(part[(size_t)(seg * BB + b) * DD + t]);
        sbjb[t] = f2bf(s * inv);
    }
    // epilogue operand prefetch
    int lab1[4], lab2[4], mk[4];
#pragma unroll
    for (int i = 0; i < 4; i++) {
        const int l = (m0w + quad * 4 + i) & (LL - 1);
        lab1[i] = obj_s[b * LL + l];
        lab2[i] = obj_e[b * LL + l] + CC;
        mk[i]   = mask[b * LL + l];
    }
    // convert A -> bf16 regs (waits land progressively; a[] dies here)
    bf16x8 areg[16];
#pragma unroll
    for (int j = 0; j < 16; j++) {
        float4 v0 = a[2 * j], v1 = a[2 * j + 1];
        bf16x8 af;
        af[0] = (short)f2bf(v0.x); af[1] = (short)f2bf(v0.y);
        af[2] = (short)f2bf(v0.z); af[3] = (short)f2bf(v0.w);
        af[4] = (short)f2bf(v1.x); af[5] = (short)f2bf(v1.y);
        af[6] = (short)f2bf(v1.z); af[7] = (short)f2bf(v1.w);
        areg[j] = af;
    }
    __syncthreads();

    // ---- phase 1: scomb strips (waves 0..6), broadcast-A MFMA ----
    if (wv < 7) {
        const unsigned short* wbot = (const unsigned short*)(wsb + WSB_WBOT);
        const unsigned short* Bf = wbot + (size_t)(wv * 16 + tc) * DD + quad * 8;
        const unsigned short* Af2 = sbjb + quad * 8;
        f32x4 sacc = (f32x4)(0.0f);
#pragma unroll
        for (int kk = 0; kk < DD; kk += 32) {
            bf16x8 af = *(const bf16x8*)(Af2 + kk);
            bf16x8 bf = *(const bf16x8*)(Bf + kk);
            sacc = __builtin_amdgcn_mfma_f32_16x16x32_bf16(af, bf, sacc, 0, 0, 0);
        }
        if (ln < 16) {
            const int cc = wv * 16 + ln;
            const float bias =
                (cc < CC) ? bst[cc] : ((cc < NC) ? ben[cc - CC] : 0.0f);
            scl[cc] = sacc[0] + bias;
        }
    }

    // ---- phase 2: main burst, pure LDS+MFMA ----
    f32x4 acc[7];
#pragma unroll
    for (int u = 0; u < 7; u++) acc[u] = (f32x4)(0.0f);
    const unsigned short* Wf = Wt + tc * WST + quad * 8;

#pragma unroll
    for (int j = 0; j < 16; j++) {
        bf16x8 af = areg[j];
#pragma unroll
        for (int u = 0; u < 7; u++) {
            bf16x8 bf = *(const bf16x8*)(Wf + u * 16 * WST + j * 32);
            acc[u] = __builtin_amdgcn_mfma_f32_16x16x32_bf16(af, bf, acc[u], 0, 0, 0);
        }
    }
    __syncthreads();        // scl ready for all waves

    // ---- fused CE epilogue (C/D: col=lane&15, row=quad*4+reg) ----
    float sc[7];
#pragma unroll
    for (int u = 0; u < 7; u++) sc[u] = scl[u * 16 + tc];

    float loss_local = 0.0f, cnt_local = 0.0f;
#pragma unroll
    for (int i = 0; i < 4; i++) {
        float lg[7];
#pragma unroll
        for (int u = 0; u < 7; u++) lg[u] = acc[u][i] + sc[u];
        float m1 = fmaxf(fmaxf(lg[0], lg[1]), lg[2]);
        if (tc < 2) m1 = fmaxf(m1, lg[3]);
        float m2 = fmaxf(lg[4], lg[5]);
        if (tc >= 2) m2 = fmaxf(m2, lg[3]);
        if (tc < 4)  m2 = fmaxf(m2, lg[6]);
#pragma unroll
        for (int off = 1; off < 16; off <<= 1) {
            m1 = fmaxf(m1, __shfl_xor(m1, off, 16));
            m2 = fmaxf(m2, __shfl_xor(m2, off, 16));
        }
        float e1 = expf(lg[0] - m1) + expf(lg[1] - m1) + expf(lg[2] - m1)
                 + ((tc < 2) ? expf(lg[3] - m1) : 0.0f);
        float e2 = expf(lg[4] - m2) + expf(lg[5] - m2)
                 + ((tc >= 2) ? expf(lg[3] - m2) : 0.0f)
                 + ((tc < 4)  ? expf(lg[6] - m2) : 0.0f);
        float t1 = 0.0f, t2 = 0.0f;
#pragma unroll
        for (int u = 0; u < 7; u++) {
            const int cc = u * 16 + tc;
            if (cc == lab1[i]) t1 = lg[u];
            if (cc == lab2[i]) t2 = lg[u];
        }
#pragma unroll
        for (int off = 1; off < 16; off <<= 1) {
            e1 += __shfl_xor(e1, off, 16);
            e2 += __shfl_xor(e2, off, 16);
            t1 += __shfl_xor(t1, off, 16);
            t2 += __shfl_xor(t2, off, 16);
        }
        if (tc == 0) {
            const float nll = (m1 + logf(e1) - t1) + (m2 + logf(e2) - t2);
            loss_local += mk[i] ? nll : 0.0f;
            cnt_local  += mk[i] ? 1.0f : 0.0f;
        }
    }
#pragma unroll
    for (int off = 1; off < 64; off <<= 1) {
        loss_local += __shfl_xor(loss_local, off);
        cnt_local  += __shfl_xor(cnt_local, off);
    }
    if (ln == 0) { red[wv * 2] = loss_local; red[wv * 2 + 1] = cnt_local; }
    __syncthreads();
    if (t == 0) {
        float Ls = 0.f, Cs = 0.f;
#pragma unroll
        for (int w = 0; w < 8; w++) { Ls += red[w * 2]; Cs += red[w * 2 + 1]; }
        float* wsf = (float*)wsb;
        atomicAdd(&wsf[0], Ls);
        atomicAdd(&wsf[1], Cs);
        __threadfence();
        int old = atomicAdd((int*)(wsb + WSB_DONE), 1);
        if (old == (int)gridDim.x - 1) {
            float L = atomicAdd(&wsf[0], 0.0f);   // coherent read
            float C = atomicAdd(&wsf[1], 0.0f);
            out[0] = L / C;
        }
    }
}

extern "C" void kernel_launch(void* const* d_in, const int* in_sizes, int n_in,
                              void* d_out, int out_size, void* d_ws, size_t ws_size,
                              hipStream_t stream) {
    const float* tv   = (const float*)d_in[0];
    const int*   mask = (const int*)d_in[1];
    const int*   sbj  = (const int*)d_in[2];
    const int*   objs = (const int*)d_in[3];
    const int*   obje = (const int*)d_in[4];
    const float* Wst  = (const float*)d_in[5];
    const float* bst  = (const float*)d_in[6];
    const float* Wen  = (const float*)d_in[7];
    const float* ben  = (const float*)d_in[8];
    float* out = (float*)d_out;
    char*  wsb = (char*)d_ws;

    k_prep<<<528, 256, 0, stream>>>(tv, sbj, Wst, Wen, wsb);
    k_main<<<256, 512, 0, stream>>>(tv, mask, objs, obje, sbj, bst, ben, wsb, out);
}